// Round 4
// baseline (80.814 us; speedup 1.0000x reference)
//
#include <hip/hip_runtime.h>

// LoKr: out[b, l*64+k] = sum_{m,n} x[b, m*64+n] * w1[l,m] * w2[k,n] * (1/16)
// Rank-factored per row:  P[r][n] = sum_m w1_b[m][r] x[m][n]   (contract m)
//                         Q[r][s] = sum_n P[r][n]  w2_b[n][s]  (contract n)
//                         U[r]    = sum_s Q[r][s]  w2_a[s][k]  (contract s, k=lane)
//                         y[l]    = sum_r U[r]     w1_a[r][l]  (contract r)
// R4: prep kernel writes w1_b^T [r][m] and w1_a*(1/16) [r][l] into d_ws so the
// big contractions read weights as contiguous 64B rows -> s_load_dwordx16,
// 1 SMEM instr per 16 FMAs (was 1 per 4). x row fully resident in 64 VGPRs.

#define WAVES_PER_BLOCK 4

__device__ __forceinline__ void lds_fence() {
    asm volatile("s_waitcnt lgkmcnt(0)" ::: "memory");
}

__global__ void lokr_prep(const float* __restrict__ w1_a,
                          const float* __restrict__ w1_b,
                          float* __restrict__ ws) {
    const int i = threadIdx.x;                 // 1024 threads
    const int m = i >> 4, r = i & 15;
    ws[r * 64 + m]  = w1_b[i];                 // w1bT: [r][m]
    ws[1024 + i]    = w1_a[i] * 0.0625f;       // w1as: [r][l], prescaled
}

__global__ __launch_bounds__(256, 4) void lokr_kernel(
    const float* __restrict__ x,
    const float* __restrict__ w2_a,   // (16, 64) [s][k]
    const float* __restrict__ w2_b,   // (64, 16) [n][s]
    const float* __restrict__ wpre,   // ws: w1bT (16x64) | w1as (16x64)
    float* __restrict__ out)
{
    __shared__ __align__(16) float s_P[WAVES_PER_BLOCK][16][65];  // conflict-free
    __shared__ __align__(16) float s_Q[WAVES_PER_BLOCK][16][16];

    const float* __restrict__ w1bT = wpre;         // [r][m]
    const float* __restrict__ w1as = wpre + 1024;  // [r][l]

    const int tid  = threadIdx.x;
    const int wave = tid >> 6;
    const int lane = tid & 63;
    const int b    = blockIdx.x * WAVES_PER_BLOCK + wave;   // one row per wave

    // per-lane w2_a column (coalesced, once)
    float w2a[16];
#pragma unroll
    for (int s = 0; s < 16; ++s) w2a[s] = w2_a[s * 64 + lane];

    // ---- load full x row: 64 loads in flight, staged vmcnt drains ----
    const float* xb = x + (size_t)b * 4096 + lane;
    float xv[64];
#pragma unroll
    for (int m = 0; m < 64; ++m) xv[m] = xb[m * 64];        // 256 B/wave each

    // ---- S1: accP[r] = sum_m w1bT[r][m] * xv[m] ----
    // weights: contiguous uniform 64B rows -> s_load_dwordx16; 16 indep chains
    float accP[16];
#pragma unroll
    for (int r = 0; r < 16; ++r) accP[r] = 0.f;

#pragma unroll
    for (int mb = 0; mb < 4; ++mb) {
#pragma unroll
        for (int r = 0; r < 16; ++r) {
            const float* wrow = w1bT + r * 64 + mb * 16;    // uniform -> s_load
#pragma unroll
            for (int i = 0; i < 16; ++i)
                accP[r] += wrow[i] * xv[mb * 16 + i];
        }
    }

    // ---- S2: Q[rq][s0..s0+3] via per-wave LDS P scratch ----
    const int rq = lane >> 2;          // 0..15
    const int s0 = (lane & 3) * 4;     // 0,4,8,12
#pragma unroll
    for (int r = 0; r < 16; ++r) s_P[wave][r][lane] = accP[r];
    lds_fence();                                   // P visible wave-wide

    float q0 = 0.f, q1 = 0.f, q2 = 0.f, q3 = 0.f;
#pragma unroll 16
    for (int n = 0; n < 64; ++n) {
        const float pv = s_P[wave][rq][n];         // 16 banks, 4-lane broadcast
        const float4 wv = *(const float4*)&w2_b[n * 16 + s0];  // L1-hot
        q0 += pv * wv.x; q1 += pv * wv.y; q2 += pv * wv.z; q3 += pv * wv.w;
    }
    float4 qv4; qv4.x = q0; qv4.y = q1; qv4.z = q2; qv4.w = q3;
    *(float4*)&s_Q[wave][rq][s0] = qv4;
    lds_fence();                                   // Q visible wave-wide

    // ---- S3: U[r] = sum_s Q[r][s] * w2a[s] ----
    float U[16];
#pragma unroll
    for (int r = 0; r < 16; ++r) {
        float acc = 0.f;
#pragma unroll
        for (int s4 = 0; s4 < 4; ++s4) {
            const float4 qv = *(const float4*)&s_Q[wave][r][s4 * 4];  // broadcast
            acc += qv.x * w2a[s4 * 4 + 0];
            acc += qv.y * w2a[s4 * 4 + 1];
            acc += qv.z * w2a[s4 * 4 + 2];
            acc += qv.w * w2a[s4 * 4 + 3];
        }
        U[r] = acc;
    }

    // ---- S4: y[l] = sum_r w1as[r][l] * U[r]  (scale pre-folded) ----
    // weights: contiguous uniform 64B rows -> s_load_dwordx16; 64 indep chains
    float y[64];
#pragma unroll
    for (int l = 0; l < 64; ++l) y[l] = 0.f;
#pragma unroll
    for (int r = 0; r < 16; ++r) {
        const float ur = U[r];
        const float* wrow = w1as + r * 64;                  // uniform -> s_load
#pragma unroll
        for (int l = 0; l < 64; ++l)
            y[l] += wrow[l] * ur;
    }

    float* op = out + (size_t)b * 4096 + lane;
#pragma unroll
    for (int l = 0; l < 64; ++l)
        op[l * 64] = y[l];                         // 256 B/wave, coalesced
}

extern "C" void kernel_launch(void* const* d_in, const int* in_sizes, int n_in,
                              void* d_out, int out_size, void* d_ws, size_t ws_size,
                              hipStream_t stream) {
    const float* x    = (const float*)d_in[0];
    const float* w1_a = (const float*)d_in[1];
    const float* w1_b = (const float*)d_in[2];
    const float* w2_a = (const float*)d_in[3];
    const float* w2_b = (const float*)d_in[4];
    float* out = (float*)d_out;
    float* ws  = (float*)d_ws;    // needs 8 KB

    hipLaunchKernelGGL(lokr_prep, dim3(1), dim3(1024), 0, stream, w1_a, w1_b, ws);

    dim3 grid(2048), block(256);  // 8192 rows / 4 waves/block
    hipLaunchKernelGGL(lokr_kernel, grid, block, 0, stream,
                       x, w2_a, w2_b, ws, out);
}

// Round 5
// 75.384 us; speedup vs baseline: 1.0720x; 1.0720x over previous
//
#include <hip/hip_runtime.h>
#include <stdint.h>

// LoKr: out[b, l*64+k] = (1/16) * sum_{m,n} x[b, m*64+n] * w1[l,m] * w2[k,n]
// Rank-factored per row:  P[r][n] = sum_m w1_b[m][r] x[m][n]   (contract m)
//                         Q[r][s] = sum_n P[r][n]  w2_b[n][s]  (contract n)
//                         U[r]    = sum_s Q[r][s]  w2a[s][k]   (contract s, k=lane)
//                         y[l]    = sum_r U[r]     w1_a[r][l]  (contract r)
// R5: x streamed via global_load_lds DMA (wave-local 4-buffer ring, 8-m chunks,
// counted vmcnt(6) steady-state, never drained mid-loop). DMA needs no VGPRs ->
// compiler can't destroy the pipeline depth. Weights via scalar s_load path.

#define WPB   4     // waves per block
#define RING  4     // LDS ring buffers per wave
#define CH_M  8     // m-rows per chunk (2 KB = 2 DMA instrs of 1 KB)
#define NCH   8     // chunks per row (64 m)

typedef __attribute__((address_space(3))) void       lds_void;
typedef const __attribute__((address_space(1))) void g_void;

__device__ __forceinline__ void lds_fence() {
    asm volatile("s_waitcnt lgkmcnt(0)" ::: "memory");
}

__global__ __launch_bounds__(256, 3) void lokr_kernel(
    const float* __restrict__ x,
    const float* __restrict__ w1_a,   // (16, 64) [r][l]
    const float* __restrict__ w1_b,   // (64, 16) [m][r]
    const float* __restrict__ w2_a,   // (16, 64) [s][k]
    const float* __restrict__ w2_b,   // (64, 16) [n][s]
    float* __restrict__ out)
{
    // 32 KB x-ring + 16.25 KB P + 4 KB Q = 52.3 KB -> 3 blocks/CU
    __shared__ __align__(16) float sx[WPB][RING][CH_M][64];
    __shared__ __align__(16) float sP[WPB][16][65];   // bank=(r+n)%32: conflict-free
    __shared__ __align__(16) float sQ[WPB][16][16];

    const int tid  = threadIdx.x;
    const int wave = tid >> 6;
    const int lane = tid & 63;
    const int b    = blockIdx.x * WPB + wave;          // one row per wave

    const float* xrow = x + (size_t)b * 4096;
    const int lane_m = lane >> 4;          // 0..3 (m sub-row within 1 KB DMA)
    const int lane_n = (lane & 15) << 2;   // 0,4,..,60 (4 consecutive n)

    // DMA one 2 KB chunk (8 m-rows) into ring buffer c&3.
    // LDS dest is linear (uniform base + lane*16B); per-lane global source
    // chosen so LDS holds row-major [m][n]:  lane*16B == (lane>>4)*64 + (lane&15)*4 dwords.
    auto issue_chunk = [&](int c) {
        const float* gp0 = xrow + (c * CH_M + 0 + lane_m) * 64 + lane_n;
        const float* gp1 = xrow + (c * CH_M + 4 + lane_m) * 64 + lane_n;
        __builtin_amdgcn_global_load_lds((g_void*)gp0, (lds_void*)&sx[wave][c & (RING - 1)][0][0], 16, 0, 0);
        __builtin_amdgcn_global_load_lds((g_void*)gp1, (lds_void*)&sx[wave][c & (RING - 1)][4][0], 16, 0, 0);
    };

    // ---- S1: accP[r] = sum_m w1_b[m][r] * x[m][lane], DMA-pipelined ----
    issue_chunk(0); issue_chunk(1); issue_chunk(2);    // 3 chunks (6 instrs) in flight

    float accP[16];
#pragma unroll
    for (int r = 0; r < 16; ++r) accP[r] = 0.f;

#pragma unroll
    for (int c = 0; c < NCH; ++c) {
        __builtin_amdgcn_sched_barrier(0);   // fence: DMA below can't hoist above prior chunk's reads
        if (c + 3 < NCH) issue_chunk(c + 3); // ring slot (c+3)&3 != c&3: no overwrite of live buf
        // counted waits: steady-state keeps 3 chunks (6 instrs) in flight
        if      (c <= NCH - 4) asm volatile("s_waitcnt vmcnt(6)" ::: "memory");
        else if (c == NCH - 3) asm volatile("s_waitcnt vmcnt(4)" ::: "memory");
        else if (c == NCH - 2) asm volatile("s_waitcnt vmcnt(2)" ::: "memory");
        else                   asm volatile("s_waitcnt vmcnt(0)" ::: "memory");
        __builtin_amdgcn_sched_barrier(0);

        float xv[CH_M];
#pragma unroll
        for (int mm = 0; mm < CH_M; ++mm)
            xv[mm] = sx[wave][c & (RING - 1)][mm][lane];   // ds_read_b32, 2-way alias: free
        __builtin_amdgcn_sched_barrier(0);   // pin ds_reads before SMEM weight loads (lgkm mixing)

#pragma unroll
        for (int mm = 0; mm < CH_M; ++mm) {
            const int m = c * CH_M + mm;
            const float xm = xv[mm];
#pragma unroll
            for (int r4 = 0; r4 < 4; ++r4) {
                const float4 wv = *(const float4*)&w1_b[m * 16 + r4 * 4];  // uniform -> s_load
                accP[r4 * 4 + 0] += wv.x * xm;
                accP[r4 * 4 + 1] += wv.y * xm;
                accP[r4 * 4 + 2] += wv.z * xm;
                accP[r4 * 4 + 3] += wv.w * xm;
            }
        }
    }

    // ---- S2: Q[rq][s0..s0+3] via per-wave LDS P scratch ----
    const int rq = lane >> 2;          // 0..15
    const int s0 = (lane & 3) * 4;     // 0,4,8,12
#pragma unroll
    for (int r = 0; r < 16; ++r) sP[wave][r][lane] = accP[r];
    lds_fence();                                   // P visible wave-wide

    // per-lane w2_a column; issued here so latency hides under S2
    float w2a[16];
#pragma unroll
    for (int s = 0; s < 16; ++s) w2a[s] = w2_a[s * 64 + lane];

    float q0 = 0.f, q1 = 0.f, q2 = 0.f, q3 = 0.f;
#pragma unroll 16
    for (int n = 0; n < 64; ++n) {
        const float pv = sP[wave][rq][n];          // 16 banks, 4-lane broadcast
        const float4 wv = *(const float4*)&w2_b[n * 16 + s0];  // one 64B line/wave, L1-hot
        q0 += pv * wv.x; q1 += pv * wv.y; q2 += pv * wv.z; q3 += pv * wv.w;
    }
    float4 qv4; qv4.x = q0; qv4.y = q1; qv4.z = q2; qv4.w = q3;
    *(float4*)&sQ[wave][rq][s0] = qv4;
    lds_fence();                                   // Q visible wave-wide

    // ---- S3: U[r] = (1/16) * sum_s Q[r][s] * w2a[s] (scale folded here) ----
    float U[16];
#pragma unroll
    for (int r = 0; r < 16; ++r) {
        float acc = 0.f;
#pragma unroll
        for (int s4 = 0; s4 < 4; ++s4) {
            const float4 qv = *(const float4*)&sQ[wave][r][s4 * 4];  // uniform broadcast
            acc += qv.x * w2a[s4 * 4 + 0];
            acc += qv.y * w2a[s4 * 4 + 1];
            acc += qv.z * w2a[s4 * 4 + 2];
            acc += qv.w * w2a[s4 * 4 + 3];
        }
        U[r] = acc * 0.0625f;
    }

    // ---- S4: y[l] = sum_r w1_a[r][l] * U[r]; two 32-wide halves ----
    float* op = out + (size_t)b * 4096 + lane;
#pragma unroll
    for (int h = 0; h < 2; ++h) {
        float y[32];
#pragma unroll
        for (int l = 0; l < 32; ++l) y[l] = 0.f;
#pragma unroll 4
        for (int r = 0; r < 16; ++r) {
            const float ur = U[r];
            const float* wrow = w1_a + r * 64 + h * 32;     // contiguous, uniform -> s_load
#pragma unroll
            for (int l4 = 0; l4 < 8; ++l4) {
                const float4 wv = *(const float4*)&wrow[l4 * 4];
                y[l4 * 4 + 0] += wv.x * ur;
                y[l4 * 4 + 1] += wv.y * ur;
                y[l4 * 4 + 2] += wv.z * ur;
                y[l4 * 4 + 3] += wv.w * ur;
            }
        }
#pragma unroll
        for (int l = 0; l < 32; ++l)
            op[(h * 32 + l) * 64] = y[l];          // 256 B/wave, coalesced
    }
}

extern "C" void kernel_launch(void* const* d_in, const int* in_sizes, int n_in,
                              void* d_out, int out_size, void* d_ws, size_t ws_size,
                              hipStream_t stream) {
    const float* x    = (const float*)d_in[0];
    const float* w1_a = (const float*)d_in[1];
    const float* w1_b = (const float*)d_in[2];
    const float* w2_a = (const float*)d_in[3];
    const float* w2_b = (const float*)d_in[4];
    float* out = (float*)d_out;

    // 8192 rows / (4 waves * 1 row/wave) = 2048 blocks
    dim3 grid(2048), block(256);
    hipLaunchKernelGGL(lokr_kernel, grid, block, 0, stream,
                       x, w1_a, w1_b, w2_a, w2_b, out);
}

// Round 7
// 49.329 us; speedup vs baseline: 1.6383x; 1.5282x over previous
//
#include <hip/hip_runtime.h>

// LoKr via layout-chained MFMA (f16 inputs, fp32 accum), zero LDS.
// Per batch row b, with Xb = reshape(x[b], 64m x 64n):
//   PT(64n x 16r) = Xb^T @ w1b          (contract m, 16 mfma)
//   QT(16s x 16r) = w2b^T @ PT          (contract n,  4 mfma)
//   U (16r x 64k) = Q @ w2a             (contract s,  4 mfma)
//   y (64l x 64k) = (w1a^T/16) @ U      (contract r, 16 mfma)
// All with v_mfma_f32_16x16x16_f16. Key property: C-frag layout
// (col=lane&15, row=(lane>>4)*4+reg) == A/B-frag layout (m|n=lane&15,
// k=(lane>>4)*4+j) at every junction -> chain stays in registers,
// only v_cvt_pkrtz between stages. No LDS, no SMEM in the loop.

typedef __fp16 h2 __attribute__((ext_vector_type(2)));
typedef __fp16 h4 __attribute__((ext_vector_type(4)));
typedef float  f4 __attribute__((ext_vector_type(4)));

__device__ __forceinline__ h4 pack4(float a, float b, float c, float d) {
    h2 lo = __builtin_amdgcn_cvt_pkrtz(a, b);
    h2 hi = __builtin_amdgcn_cvt_pkrtz(c, d);
    h4 r;
    r[0] = lo[0]; r[1] = lo[1]; r[2] = hi[0]; r[3] = hi[1];
    return r;
}

#define MFMA16(a, b, c) __builtin_amdgcn_mfma_f32_16x16x16f16((a), (b), (c), 0, 0, 0)

#define ROWS 4   // rows per wave; 512 blocks x 4 waves x 4 rows = 8192

__global__ __launch_bounds__(256) void lokr_kernel(
    const float* __restrict__ x,
    const float* __restrict__ w1_a,   // (16, 64) [r][l]
    const float* __restrict__ w1_b,   // (64, 16) [m][r]
    const float* __restrict__ w2_a,   // (16, 64) [s][k]
    const float* __restrict__ w2_b,   // (64, 16) [n][s]
    float* __restrict__ out)
{
    const int lane = threadIdx.x & 63;
    const int g    = lane >> 4;        // 0..3  (k-group / row-group)
    const int c    = lane & 15;        // 0..15 (col within fragment)
    const int gw   = blockIdx.x * 4 + (threadIdx.x >> 6);
    const size_t b0 = (size_t)gw * ROWS;

    // ---- static weight fragments (once per wave, L2-hot) ----
    // W1B[t]:  B-frag of S1: element j = w1_b[m=t*16+g*4+j][r=c]
    // W2BT[t]: A-frag of S2: element j = w2b^T[s=c][n=t*16+g*4+j] = w2_b[n][s]
    // W2A[t]:  B-frag of S3: element j = w2_a[s=g*4+j][k=t*16+c]
    // W1AT[t]: A-frag of S4: element j = w1_a[r=g*4+j][l=t*16+c] * (1/16)
    h4 W1B[4], W2BT[4], W2A[4], W1AT[4];
#pragma unroll
    for (int t = 0; t < 4; ++t) {
        const int kb = t * 16 + g * 4;
        W1B[t]  = pack4(w1_b[(kb+0)*16 + c], w1_b[(kb+1)*16 + c],
                        w1_b[(kb+2)*16 + c], w1_b[(kb+3)*16 + c]);
        W2BT[t] = pack4(w2_b[(kb+0)*16 + c], w2_b[(kb+1)*16 + c],
                        w2_b[(kb+2)*16 + c], w2_b[(kb+3)*16 + c]);
        W2A[t]  = pack4(w2_a[(g*4+0)*64 + t*16 + c], w2_a[(g*4+1)*64 + t*16 + c],
                        w2_a[(g*4+2)*64 + t*16 + c], w2_a[(g*4+3)*64 + t*16 + c]);
        W1AT[t] = pack4(w1_a[(g*4+0)*64 + t*16 + c] * 0.0625f,
                        w1_a[(g*4+1)*64 + t*16 + c] * 0.0625f,
                        w1_a[(g*4+2)*64 + t*16 + c] * 0.0625f,
                        w1_a[(g*4+3)*64 + t*16 + c] * 0.0625f);
    }

    const f4 zero = {0.f, 0.f, 0.f, 0.f};

#pragma unroll 1
    for (int rr = 0; rr < ROWS; ++rr) {
        const float* xp = x + (b0 + rr) * 4096;

        // ---- load Xb^T A-fragments: lane holds x[m=ks*16+g*4+j][n=nt*16+c]
        // 64 independent dword loads (4x64B segments each), all in flight.
        float xf[4][4][4];
#pragma unroll
        for (int nt = 0; nt < 4; ++nt)
#pragma unroll
            for (int ks = 0; ks < 4; ++ks)
#pragma unroll
                for (int j = 0; j < 4; ++j)
                    xf[nt][ks][j] = xp[(ks*16 + g*4 + j)*64 + nt*16 + c];

        h4 XA[4][4];
#pragma unroll
        for (int nt = 0; nt < 4; ++nt)
#pragma unroll
            for (int ks = 0; ks < 4; ++ks)
                XA[nt][ks] = pack4(xf[nt][ks][0], xf[nt][ks][1],
                                   xf[nt][ks][2], xf[nt][ks][3]);

        // ---- S1: PT[nt] (16n x 16r tile) = sum_ks Xb^T-chunk @ w1b-chunk
        f4 PT[4];
#pragma unroll
        for (int nt = 0; nt < 4; ++nt) {
            f4 acc = zero;
#pragma unroll
            for (int ks = 0; ks < 4; ++ks)
                acc = MFMA16(XA[nt][ks], W1B[ks], acc);
            PT[nt] = acc;   // C: lane -> (col r=c, row n=nt*16+g*4+reg)
        }

        // ---- S2: QT = sum_nt w2b^T-chunk @ PT[nt]  (contract n) ----
        h4 PTH[4];
#pragma unroll
        for (int nt = 0; nt < 4; ++nt)
            PTH[nt] = pack4(PT[nt][0], PT[nt][1], PT[nt][2], PT[nt][3]);
        f4 qa = zero;
#pragma unroll
        for (int nt = 0; nt < 4; ++nt)
            qa = MFMA16(W2BT[nt], PTH[nt], qa);
        // QT C: lane -> (col r=c, row s=g*4+reg); as A-frag of S3: Q[r=c][s=g*4+j]
        h4 QTH = pack4(qa[0], qa[1], qa[2], qa[3]);

        // ---- S3: U[kt] (16r x 16k tile) = Q @ w2a-tile (contract s, K=16) ----
        h4 UH[4];
#pragma unroll
        for (int kt = 0; kt < 4; ++kt) {
            f4 u = MFMA16(QTH, W2A[kt], zero);
            // U C: lane -> (col k=kt*16+c, row r=g*4+reg) == B-frag of S4
            UH[kt] = pack4(u[0], u[1], u[2], u[3]);
        }

        // ---- S4: y[lt][kt] = (w1a^T/16)-tile @ U[kt] (contract r, K=16) ----
        float* op = out + (b0 + rr) * 4096 + g * 256 + c;   // (g*4)*64 + c
#pragma unroll
        for (int lt = 0; lt < 4; ++lt) {
#pragma unroll
            for (int kt = 0; kt < 4; ++kt) {
                f4 y = MFMA16(W1AT[lt], UH[kt], zero);
                // C: lane -> (col k=kt*16+c, row l=lt*16+g*4+reg)
#pragma unroll
                for (int reg = 0; reg < 4; ++reg)
                    op[lt*1024 + reg*64 + kt*16] = y[reg];
            }
        }
    }
}

extern "C" void kernel_launch(void* const* d_in, const int* in_sizes, int n_in,
                              void* d_out, int out_size, void* d_ws, size_t ws_size,
                              hipStream_t stream) {
    const float* x    = (const float*)d_in[0];
    const float* w1_a = (const float*)d_in[1];
    const float* w1_b = (const float*)d_in[2];
    const float* w2_a = (const float*)d_in[3];
    const float* w2_b = (const float*)d_in[4];
    float* out = (float*)d_out;

    // 8192 rows / (4 waves * 4 rows/wave) = 512 blocks
    dim3 grid(512), block(256);
    hipLaunchKernelGGL(lokr_kernel, grid, block, 0, stream,
                       x, w1_a, w1_b, w2_a, w2_b, out);
}